// Round 1
// baseline (330.390 us; speedup 1.0000x reference)
//
#include <hip/hip_runtime.h>
#include <math.h>

// V=100000, D=300, B=16384, NCTX=10, NNEG=20
#define DIM    300
#define CH     75           // float4 chunks per row (1200 B, rows are 16B-aligned)
#define NCTX   10
#define NNEG   20
#define NROWS  (1 + NNEG)   // 21 out rows: [0]=center, [1..20]=negatives
#define BLOCK  128          // 2 waves/block: finer wg granularity for occupancy tail
#define WPB    (BLOCK / 64) // waves (samples) per block
#define G      7            // out-rows per batch — R3's sweet spot.
// R4 lesson: >7-element arrays get demoted to LDS (17KB, 262K conflicts).
// R5 lesson: 11-deep batches + __launch_bounds__(,4) make the scheduler
// SERIALIZE loads (VGPR 36, VALUBusy 10%, 250us). Keep G=7, no min-waves hint.
// R6 (this round): b is wave-uniform -> readfirstlane(b) so ALL 31 indices
// become s_load into SGPRs; row gathers become saddr-form global_load_dwordx4
// sharing two lane-offset VGPRs. Kills 31 ds_bpermute broadcasts + ~400 VALU
// 64-bit address instrs per sample that sat on the gather critical path.

__device__ __forceinline__ float logsig_fast(float x) {
    // min(x,0) - log(1+exp(-|x|)) with native v_exp/v_log. abs err ~1e-6;
    // test threshold is 0.29 on a ~14.5 loss — orders of margin.
    return fminf(x, 0.f) - __logf(1.f + __expf(-fabsf(x)));
}
__device__ __forceinline__ float dot4(float4 a, float4 b) {
    return a.x * b.x + a.y * b.y + a.z * b.z + a.w * b.w;
}
__device__ __forceinline__ float4 add4(float4 a, float4 b) {
    return make_float4(a.x + b.x, a.y + b.y, a.z + b.z, a.w + b.w);
}

__global__ __launch_bounds__(BLOCK) void cbow_loss_kernel(
    const int*   __restrict__ ctx,     // [B, NCTX]
    const int*   __restrict__ center,  // [B]
    const int*   __restrict__ neg,     // [B, NNEG]
    const float* __restrict__ in_w,    // [V, D]
    const float* __restrict__ out_w,   // [V, D]
    float*       __restrict__ out,     // [1], zeroed on-stream
    int B, float inv_b)
{
    __shared__ float wsum[WPB];

    const int tid  = threadIdx.x;
    const int wave = tid >> 6;
    const int lane = tid & 63;
    // Wave-uniform sample id, forced into an SGPR so downstream index loads
    // are provably uniform -> s_load, and row bases live in SGPRs.
    const int b = __builtin_amdgcn_readfirstlane(blockIdx.x * WPB + wave);

    float loss = 0.f;
    if (b < B) {
        // Chunk ownership: c1=lane (always valid), c2=64+lane (lanes 0..10).
        // Invalid lanes clamp-load chunk 74 (same-line broadcast), zeroed via s1.
        const int   c1 = lane;
        const int   c2 = (64 + lane < CH) ? 64 + lane : CH - 1;
        const float w1 = (64 + lane < CH) ? 1.f : 0.f;

        // ---- Phase 1: ctx mean in registers. 20 independent saddr loads.
        float4 a0 = make_float4(0.f, 0.f, 0.f, 0.f);
        float4 a1 = make_float4(0.f, 0.f, 0.f, 0.f);
        #pragma unroll
        for (int j = 0; j < NCTX; ++j) {
            const int w = ctx[b * NCTX + j];   // uniform -> s_load, SGPR
            const float4* row = (const float4*)(in_w + (long long)w * DIM);
            a0 = add4(a0, row[c1]);
            a1 = add4(a1, row[c2]);
        }
        const float s0 = 1.f / NCTX;
        const float s1 = w1 / NCTX;
        const float4 m0 = make_float4(a0.x * s0, a0.y * s0, a0.z * s0, a0.w * s0);
        const float4 m1 = make_float4(a1.x * s1, a1.y * s1, a1.z * s1, a1.w * s1);

        // Out-row indices: all uniform, land in SGPRs (static indexing only).
        int oidx[NROWS];
        oidx[0] = center[b];                   // uniform -> s_load
        #pragma unroll
        for (int k = 0; k < NNEG; ++k)
            oidx[1 + k] = neg[b * NNEG + k];   // uniform -> s_load

        // ---- Phase 2: 21 dots in 3 batches of 7 (14 independent loads per
        // batch; batch t+1 loads overlap batch t reduction).
        #pragma unroll
        for (int t = 0; t < 3; ++t) {
            float4 r0[G], r1[G];
            #pragma unroll
            for (int k = 0; k < G; ++k) {
                const int w = oidx[t * G + k]; // SGPR
                const float4* row = (const float4*)(out_w + (long long)w * DIM);
                r0[k] = row[c1];
                r1[k] = row[c2];
            }
            float p[G];
            #pragma unroll
            for (int k = 0; k < G; ++k)
                p[k] = dot4(r0[k], m0) + dot4(r1[k], m1);
            #pragma unroll
            for (int off = 32; off > 0; off >>= 1) {
                #pragma unroll
                for (int k = 0; k < G; ++k)
                    p[k] += __shfl_down(p[k], off, 64);
            }
            if (lane == 0) {
                #pragma unroll
                for (int k = 0; k < G; ++k) {
                    const int i = t * G + k;
                    loss += logsig_fast(i == 0 ? p[k] : -p[k]);
                }
            }
        }
    }

    if (lane == 0) wsum[wave] = loss;
    __syncthreads();
    if (tid == 0)
        atomicAdd(out, -(wsum[0] + wsum[1]) * inv_b);
}

extern "C" void kernel_launch(void* const* d_in, const int* in_sizes, int n_in,
                              void* d_out, int out_size, void* d_ws, size_t ws_size,
                              hipStream_t stream) {
    const int*   ctx    = (const int*)  d_in[0];
    const int*   center = (const int*)  d_in[1];
    const int*   neg    = (const int*)  d_in[2];
    const float* in_w   = (const float*)d_in[3];
    const float* out_w  = (const float*)d_in[4];
    float*       out    = (float*)d_out;

    const int B = in_sizes[1];  // center_word is [B]

    hipMemsetAsync(out, 0, sizeof(float), stream);
    cbow_loss_kernel<<<(B + WPB - 1) / WPB, BLOCK, 0, stream>>>(
        ctx, center, neg, in_w, out_w, out, B, 1.0f / (float)B);
}

// Round 2
// 289.705 us; speedup vs baseline: 1.1404x; 1.1404x over previous
//
#include <hip/hip_runtime.h>
#include <math.h>

// V=100000, D=300, B=16384, NCTX=10, NNEG=20
#define DIM    300
#define CH     75           // float4 chunks per row (1200 B, rows 16B-aligned)
#define NCTX   10
#define NNEG   20
#define NROWS  (1 + NNEG)   // 21 out rows: [0]=center, [1..20]=negatives
#define BLOCK  256          // 4 waves/block, one sample per wave (R0 proven base)
#define G      7            // out-rows per batch. R4: >7-elem arrays demote to LDS.
// R6 LESSON (scalar-index experiment, 158us vs 121us): readfirstlane(b) +
// s_load indices reduced VALUBusy 20->14% but REGRESSED — VALU addr math was
// never the critical path. Warm-L3 replays run at the SAME duration as cold
// ones => kernel is LATENCY-bound, not BW-bound. Keep vector-index + shfl.
// R7 (this round): the real wall is MLP. At VGPR=40 the compiler cannot hold
// two G=7 batches, so every shfl-reduce+logsig window (~600cy) has ZERO loads
// in flight. Explicit double-buffer (rA/rB statically named, rule #20) keeps
// 14 loads outstanding through reductions. Costs occupancy (8->3 waves/SIMD),
// buys ~4x outstanding requests/CU — the binding resource.

__device__ __forceinline__ float logsig_fast(float x) {
    // min(x,0) - log(1+exp(-|x|)) with native v_exp/v_log. abs err ~1e-6;
    // test threshold is 0.29 on a ~14.5 loss — orders of margin.
    return fminf(x, 0.f) - __logf(1.f + __expf(-fabsf(x)));
}
__device__ __forceinline__ float dot4(float4 a, float4 b) {
    return a.x * b.x + a.y * b.y + a.z * b.z + a.w * b.w;
}
__device__ __forceinline__ float4 add4(float4 a, float4 b) {
    return make_float4(a.x + b.x, a.y + b.y, a.z + b.z, a.w + b.w);
}

__global__ __launch_bounds__(BLOCK) void cbow_loss_kernel(
    const int*   __restrict__ ctx,     // [B, NCTX]
    const int*   __restrict__ center,  // [B]
    const int*   __restrict__ neg,     // [B, NNEG]
    const float* __restrict__ in_w,    // [V, D]
    const float* __restrict__ out_w,   // [V, D]
    float*       __restrict__ out,     // [1], zeroed on-stream
    int B, float inv_b)
{
    __shared__ float wsum[4];

    const int tid  = threadIdx.x;
    const int wave = tid >> 6;
    const int lane = tid & 63;
    const int b    = blockIdx.x * 4 + wave;   // one sample per wave

    float loss = 0.f;
    if (b < B) {
        // Lanes hold the 31 word indices; row addresses broadcast via __shfl.
        int myidx = 0;
        if (lane < NCTX)              myidx = ctx[b * NCTX + lane];
        else if (lane == NCTX)        myidx = center[b];
        else if (lane < NCTX + NROWS) myidx = neg[b * NNEG + (lane - NCTX - 1)];

        // Chunk ownership: c1=lane (always valid), c2=64+lane (lanes 0..10).
        // Invalid lanes clamp-load chunk 74 (same-line broadcast), zeroed via s1.
        const int   c1 = lane;
        const int   c2 = (64 + lane < CH) ? 64 + lane : CH - 1;
        const float w1 = (64 + lane < CH) ? 1.f : 0.f;

        // ---- Phase 1: ctx mean. 20 independent loads, 2 accumulator pairs
        // (shortens the strict FP add chain; adds reassociable — threshold 0.29).
        float4 e0 = make_float4(0.f, 0.f, 0.f, 0.f);
        float4 e1 = make_float4(0.f, 0.f, 0.f, 0.f);
        float4 o0 = make_float4(0.f, 0.f, 0.f, 0.f);
        float4 o1 = make_float4(0.f, 0.f, 0.f, 0.f);
        #pragma unroll
        for (int j = 0; j < NCTX; j += 2) {
            const int wA = __shfl(myidx, j, 64);
            const int wB = __shfl(myidx, j + 1, 64);
            const float4* rowA = (const float4*)(in_w + (long long)wA * DIM);
            const float4* rowB = (const float4*)(in_w + (long long)wB * DIM);
            e0 = add4(e0, rowA[c1]);
            e1 = add4(e1, rowA[c2]);
            o0 = add4(o0, rowB[c1]);
            o1 = add4(o1, rowB[c2]);
        }
        const float s0 = 1.f / NCTX;
        const float s1 = w1 / NCTX;
        const float4 m0 = make_float4((e0.x + o0.x) * s0, (e0.y + o0.y) * s0,
                                      (e0.z + o0.z) * s0, (e0.w + o0.w) * s0);
        const float4 m1 = make_float4((e1.x + o1.x) * s1, (e1.y + o1.y) * s1,
                                      (e1.z + o1.z) * s1, (e1.w + o1.w) * s1);

        // ---- Phase 2: 21 dots, 3 batches of 7, explicit 2-deep pipeline.
        // Statically-named buffers (rule #20: runtime-indexed ext_vector
        // arrays go to scratch). Load batch t+1 BEFORE reducing batch t.
        float4 rA0[G], rA1[G], rB0[G], rB1[G];

#define LOADB(R0, R1, T)                                                      \
        _Pragma("unroll")                                                     \
        for (int k = 0; k < G; ++k) {                                         \
            const int w = __shfl(myidx, NCTX + (T) * G + k, 64);              \
            const float4* row = (const float4*)(out_w + (long long)w * DIM);  \
            R0[k] = row[c1];                                                  \
            R1[k] = row[c2];                                                  \
        }

#define REDUCE(R0, R1, T)                                                     \
        do {                                                                  \
            float p[G];                                                       \
            _Pragma("unroll")                                                 \
            for (int k = 0; k < G; ++k)                                       \
                p[k] = dot4(R0[k], m0) + dot4(R1[k], m1);                     \
            _Pragma("unroll")                                                 \
            for (int off = 32; off > 0; off >>= 1) {                          \
                _Pragma("unroll")                                             \
                for (int k = 0; k < G; ++k)                                   \
                    p[k] += __shfl_down(p[k], off, 64);                       \
            }                                                                 \
            if (lane == 0) {                                                  \
                _Pragma("unroll")                                             \
                for (int k = 0; k < G; ++k) {                                 \
                    const int i = (T) * G + k;                                \
                    loss += logsig_fast(i == 0 ? p[k] : -p[k]);               \
                }                                                             \
            }                                                                 \
        } while (0)

        LOADB(rA0, rA1, 0);                       // batch 0 in flight
        LOADB(rB0, rB1, 1);                       // batch 1 in flight (28 loads)
        __builtin_amdgcn_sched_barrier(0);        // don't let backend sink loads
        REDUCE(rA0, rA1, 0);                      // batch 1 covers this window
        LOADB(rA0, rA1, 2);                       // batch 2 in flight
        __builtin_amdgcn_sched_barrier(0);
        REDUCE(rB0, rB1, 1);                      // batch 2 covers this window
        REDUCE(rA0, rA1, 2);

#undef LOADB
#undef REDUCE
    }

    if (lane == 0) wsum[wave] = loss;
    __syncthreads();
    if (tid == 0)
        atomicAdd(out, -(wsum[0] + wsum[1] + wsum[2] + wsum[3]) * inv_b);
}

extern "C" void kernel_launch(void* const* d_in, const int* in_sizes, int n_in,
                              void* d_out, int out_size, void* d_ws, size_t ws_size,
                              hipStream_t stream) {
    const int*   ctx    = (const int*)  d_in[0];
    const int*   center = (const int*)  d_in[1];
    const int*   neg    = (const int*)  d_in[2];
    const float* in_w   = (const float*)d_in[3];
    const float* out_w  = (const float*)d_in[4];
    float*       out    = (float*)d_out;

    const int B = in_sizes[1];  // center_word is [B]

    hipMemsetAsync(out, 0, sizeof(float), stream);
    cbow_loss_kernel<<<(B + 3) / 4, BLOCK, 0, stream>>>(ctx, center, neg,
                                                        in_w, out_w, out,
                                                        B, 1.0f / (float)B);
}